// Round 1
// baseline (3702.673 us; speedup 1.0000x reference)
//
#include <hip/hip_runtime.h>
#include <hip/hip_bf16.h>

#define N_NODES 100000
#define IN_F 256
#define HID_F 128
#define OUT_F 32

// ---------------- GEMM1: xw = x @ W1   [N,256]x[256,128] ----------------
// block: 128 threads (one per output col), 4 rows per block.
__global__ void gemm1_kernel(const float* __restrict__ x,
                             const float* __restrict__ W1,
                             float* __restrict__ xw) {
    const int col  = threadIdx.x;          // 0..127
    const int row0 = blockIdx.x * 4;

    __shared__ float xs[4][IN_F];          // 4 KB
    for (int i = threadIdx.x; i < 4 * IN_F; i += 128) {
        int r = i >> 8, k = i & (IN_F - 1);
        xs[r][k] = x[(long long)(row0 + r) * IN_F + k];
    }
    __syncthreads();

    float acc0 = 0.f, acc1 = 0.f, acc2 = 0.f, acc3 = 0.f;
#pragma unroll 4
    for (int k = 0; k < IN_F; ++k) {
        float w = W1[k * HID_F + col];     // coalesced across cols; L2-resident
        acc0 += xs[0][k] * w;
        acc1 += xs[1][k] * w;
        acc2 += xs[2][k] * w;
        acc3 += xs[3][k] * w;
    }
    xw[(long long)(row0 + 0) * HID_F + col] = acc0;
    xw[(long long)(row0 + 1) * HID_F + col] = acc1;
    xw[(long long)(row0 + 2) * HID_F + col] = acc2;
    xw[(long long)(row0 + 3) * HID_F + col] = acc3;
}

// ---------------- GEMM2: hw = relu(h) @ W2   [N,128]x[128,32] ----------------
// block: 256 threads = 8 rows x 32 cols. W2 fully in LDS.
__global__ void gemm2_kernel(const float* __restrict__ h,
                             const float* __restrict__ W2,
                             float* __restrict__ hw) {
    const int col = threadIdx.x & 31;
    const int rl  = threadIdx.x >> 5;      // 0..7
    const int row = blockIdx.x * 8 + rl;

    __shared__ float ws[HID_F * OUT_F];    // 16 KB
    for (int i = threadIdx.x; i < HID_F * OUT_F; i += 256) ws[i] = W2[i];

    __shared__ float hs[8][HID_F];         // 4 KB
    for (int i = threadIdx.x; i < 8 * HID_F; i += 256) {
        int r = i >> 7, k = i & (HID_F - 1);
        float v = h[(long long)(blockIdx.x * 8 + r) * HID_F + k];
        hs[r][k] = v > 0.f ? v : 0.f;
    }
    __syncthreads();

    float acc = 0.f;
#pragma unroll 8
    for (int k = 0; k < HID_F; ++k)
        acc += hs[rl][k] * ws[k * OUT_F + col];
    hw[(long long)row * OUT_F + col] = acc;
}

// ---------------- SpMM (COO, atomic scatter) ----------------
// one thread per (edge, 4-feature chunk); float4 gather, 4 atomicAdds.
template <int F>
__global__ void spmm_atomic_kernel(const int* __restrict__ rows,
                                   const int* __restrict__ cols,
                                   const float* __restrict__ vals,
                                   const float* __restrict__ src,
                                   float* __restrict__ dst, int E) {
    constexpr int C = F / 4;               // chunks per edge (power of 2)
    long long idx = (long long)blockIdx.x * blockDim.x + threadIdx.x;
    int e = (int)(idx / C);
    int c = (int)(idx - (long long)e * C);
    if (e >= E) return;

    const int   r   = rows[e];
    const int   cl  = cols[e];
    const float v   = vals[e];
    const float4 s  = *(const float4*)(src + (long long)cl * F + c * 4);
    float* d = dst + (long long)r * F + c * 4;
    atomicAdd(d + 0, v * s.x);
    atomicAdd(d + 1, v * s.y);
    atomicAdd(d + 2, v * s.z);
    atomicAdd(d + 3, v * s.w);
}

extern "C" void kernel_launch(void* const* d_in, const int* in_sizes, int n_in,
                              void* d_out, int out_size, void* d_ws, size_t ws_size,
                              hipStream_t stream) {
    const float* x        = (const float*)d_in[0];
    const int*   adj_rows = (const int*)d_in[1];
    const int*   adj_cols = (const int*)d_in[2];
    const float* adj_vals = (const float*)d_in[3];
    const float* W1       = (const float*)d_in[4];
    const float* W2       = (const float*)d_in[5];
    float*       out      = (float*)d_out;
    const int E = in_sizes[1];

    float* xw = (float*)d_ws;                          // [N, 128]  51.2 MB
    float* h  = xw + (long long)N_NODES * HID_F;       // [N, 128]  51.2 MB
    float* hw = h  + (long long)N_NODES * HID_F;       // [N, 32]   12.8 MB

    // zero the scatter targets (harness poisons ws/out with 0xAA)
    hipMemsetAsync(h,   0, (size_t)N_NODES * HID_F * sizeof(float), stream);
    hipMemsetAsync(out, 0, (size_t)N_NODES * OUT_F * sizeof(float), stream);

    // xw = x @ W1
    gemm1_kernel<<<N_NODES / 4, 128, 0, stream>>>(x, W1, xw);

    // h = scatter-add(vals * xw[cols])  (F=128)
    {
        long long total = (long long)E * (HID_F / 4);
        int blocks = (int)((total + 255) / 256);
        spmm_atomic_kernel<HID_F><<<blocks, 256, 0, stream>>>(
            adj_rows, adj_cols, adj_vals, xw, h, E);
    }

    // hw = relu(h) @ W2
    gemm2_kernel<<<N_NODES / 8, 256, 0, stream>>>(h, W2, hw);

    // out = scatter-add(vals * hw[cols])  (F=32)
    {
        long long total = (long long)E * (OUT_F / 4);
        int blocks = (int)((total + 255) / 256);
        spmm_atomic_kernel<OUT_F><<<blocks, 256, 0, stream>>>(
            adj_rows, adj_cols, adj_vals, hw, out, E);
    }
}

// Round 2
// 788.242 us; speedup vs baseline: 4.6974x; 4.6974x over previous
//
#include <hip/hip_runtime.h>
#include <hip/hip_bf16.h>

#define N_NODES 100000
#define IN_F 256
#define HID_F 128
#define OUT_F 32
#define SCAN_B 256                 // elements per scan block
#define NB_SCAN ((N_NODES + SCAN_B - 1) / SCAN_B)   // 391

// ---------------- GEMM1: xw = x @ W1   [N,256]x[256,128] ----------------
__global__ void gemm1_kernel(const float* __restrict__ x,
                             const float* __restrict__ W1,
                             float* __restrict__ xw) {
    const int col  = threadIdx.x;          // 0..127
    const int row0 = blockIdx.x * 4;

    __shared__ float xs[4][IN_F];
    for (int i = threadIdx.x; i < 4 * IN_F; i += 128) {
        int r = i >> 8, k = i & (IN_F - 1);
        xs[r][k] = x[(long long)(row0 + r) * IN_F + k];
    }
    __syncthreads();

    float acc0 = 0.f, acc1 = 0.f, acc2 = 0.f, acc3 = 0.f;
#pragma unroll 4
    for (int k = 0; k < IN_F; ++k) {
        float w = W1[k * HID_F + col];
        acc0 += xs[0][k] * w;
        acc1 += xs[1][k] * w;
        acc2 += xs[2][k] * w;
        acc3 += xs[3][k] * w;
    }
    xw[(long long)(row0 + 0) * HID_F + col] = acc0;
    xw[(long long)(row0 + 1) * HID_F + col] = acc1;
    xw[(long long)(row0 + 2) * HID_F + col] = acc2;
    xw[(long long)(row0 + 3) * HID_F + col] = acc3;
}

// ---------------- GEMM2: hw = relu(h) @ W2   [N,128]x[128,32] ----------------
__global__ void gemm2_kernel(const float* __restrict__ h,
                             const float* __restrict__ W2,
                             float* __restrict__ hw) {
    const int col = threadIdx.x & 31;
    const int rl  = threadIdx.x >> 5;
    const int row = blockIdx.x * 8 + rl;

    __shared__ float ws[HID_F * OUT_F];    // 16 KB
    for (int i = threadIdx.x; i < HID_F * OUT_F; i += 256) ws[i] = W2[i];

    __shared__ float hs[8][HID_F];
    for (int i = threadIdx.x; i < 8 * HID_F; i += 256) {
        int r = i >> 7, k = i & (HID_F - 1);
        float v = h[(long long)(blockIdx.x * 8 + r) * HID_F + k];
        hs[r][k] = v > 0.f ? v : 0.f;
    }
    __syncthreads();

    float acc = 0.f;
#pragma unroll 8
    for (int k = 0; k < HID_F; ++k)
        acc += hs[rl][k] * ws[k * OUT_F + col];
    hw[(long long)row * OUT_F + col] = acc;
}

// ---------------- CSR build ----------------
__global__ void hist_kernel(const int* __restrict__ rows, int* __restrict__ cnt, int E) {
    int e = blockIdx.x * 256 + threadIdx.x;
    if (e < E) atomicAdd(&cnt[rows[e]], 1);
}

// per-block exclusive scan of 256 elements, emit block sums
__global__ void scan1_kernel(const int* __restrict__ in, int* __restrict__ out,
                             int* __restrict__ bsum, int n) {
    __shared__ int tmp[SCAN_B];
    int i = blockIdx.x * SCAN_B + threadIdx.x;
    int v = (i < n) ? in[i] : 0;
    tmp[threadIdx.x] = v;
    __syncthreads();
    for (int off = 1; off < SCAN_B; off <<= 1) {
        int t = (threadIdx.x >= off) ? tmp[threadIdx.x - off] : 0;
        __syncthreads();
        tmp[threadIdx.x] += t;
        __syncthreads();
    }
    if (i < n) out[i] = tmp[threadIdx.x] - v;   // exclusive
    if (threadIdx.x == SCAN_B - 1) bsum[blockIdx.x] = tmp[SCAN_B - 1];
}

// single-block exclusive scan of block sums (NB_SCAN <= 512)
__global__ void scan2_kernel(int* __restrict__ bsum, int n) {
    __shared__ int tmp[512];
    int v = (threadIdx.x < n) ? bsum[threadIdx.x] : 0;
    tmp[threadIdx.x] = v;
    __syncthreads();
    for (int off = 1; off < 512; off <<= 1) {
        int t = (threadIdx.x >= off) ? tmp[threadIdx.x - off] : 0;
        __syncthreads();
        tmp[threadIdx.x] += t;
        __syncthreads();
    }
    if (threadIdx.x < n) bsum[threadIdx.x] = tmp[threadIdx.x] - v;  // exclusive
}

// add block offsets -> row_ptr, init cursor, set row_ptr[N]=E
__global__ void scan3_kernel(const int* __restrict__ scanned,
                             const int* __restrict__ bsum,
                             int* __restrict__ row_ptr,
                             int* __restrict__ cursor, int n, int E) {
    int i = blockIdx.x * SCAN_B + threadIdx.x;
    if (i < n) {
        int v = scanned[i] + bsum[blockIdx.x];
        row_ptr[i] = v;
        cursor[i]  = v;
    }
    if (i == 0) row_ptr[n] = E;
}

__global__ void scatter_kernel(const int* __restrict__ rows, const int* __restrict__ cols,
                               const float* __restrict__ vals, int* __restrict__ cursor,
                               int* __restrict__ pcol, float* __restrict__ pval, int E) {
    int e = blockIdx.x * 256 + threadIdx.x;
    if (e < E) {
        int pos = atomicAdd(&cursor[rows[e]], 1);
        pcol[pos] = cols[e];
        pval[pos] = vals[e];
    }
}

// ---------------- SpMM via CSR gather ----------------
// LPR lanes cooperate on one destination row; each lane owns V consecutive floats.
template <int F, int LPR, int V>
__global__ void spmm_csr_kernel(const int* __restrict__ row_ptr,
                                const int* __restrict__ pcol,
                                const float* __restrict__ pval,
                                const float* __restrict__ src,
                                float* __restrict__ dst) {
    long long gid = (long long)blockIdx.x * blockDim.x + threadIdx.x;
    int row  = (int)(gid / LPR);
    int lane = (int)(gid & (LPR - 1));
    if (row >= N_NODES) return;

    const int e0 = row_ptr[row];
    const int e1 = row_ptr[row + 1];

    float acc[V];
#pragma unroll
    for (int i = 0; i < V; ++i) acc[i] = 0.f;

    for (int e = e0; e < e1; ++e) {
        const int   c = pcol[e];
        const float v = pval[e];
        const float* s = src + (long long)c * F + lane * V;
#pragma unroll
        for (int i = 0; i < V; ++i) acc[i] += v * s[i];
    }

    float* d = dst + (long long)row * F + lane * V;
#pragma unroll
    for (int i = 0; i < V; ++i) d[i] = acc[i];
}

extern "C" void kernel_launch(void* const* d_in, const int* in_sizes, int n_in,
                              void* d_out, int out_size, void* d_ws, size_t ws_size,
                              hipStream_t stream) {
    const float* x        = (const float*)d_in[0];
    const int*   adj_rows = (const int*)d_in[1];
    const int*   adj_cols = (const int*)d_in[2];
    const float* adj_vals = (const float*)d_in[3];
    const float* W1       = (const float*)d_in[4];
    const float* W2       = (const float*)d_in[5];
    float*       out      = (float*)d_out;
    const int E = in_sizes[1];

    // workspace carve-up
    char* p = (char*)d_ws;
    float* xw      = (float*)p;  p += (size_t)N_NODES * HID_F * sizeof(float);  // 51.2 MB
    float* h       = (float*)p;  p += (size_t)N_NODES * HID_F * sizeof(float);  // 51.2 MB
    float* hw      = (float*)p;  p += (size_t)N_NODES * OUT_F * sizeof(float);  // 12.8 MB
    int*   cnt     = (int*)p;    p += (size_t)N_NODES * sizeof(int);            // 0.4 MB
    int*   scanned = (int*)p;    p += (size_t)N_NODES * sizeof(int);            // 0.4 MB
    int*   row_ptr = (int*)p;    p += (size_t)(N_NODES + 1) * sizeof(int);
    int*   cursor  = (int*)p;    p += (size_t)N_NODES * sizeof(int);
    int*   bsum    = (int*)p;    p += 1024 * sizeof(int);
    int*   pcol    = (int*)p;    p += (size_t)E * sizeof(int);                  // 6.4 MB
    float* pval    = (float*)p;  p += (size_t)E * sizeof(float);                // 6.4 MB

    // ---- CSR build (shared by both spmm layers) ----
    hipMemsetAsync(cnt, 0, (size_t)N_NODES * sizeof(int), stream);
    hist_kernel<<<(E + 255) / 256, 256, 0, stream>>>(adj_rows, cnt, E);
    scan1_kernel<<<NB_SCAN, SCAN_B, 0, stream>>>(cnt, scanned, bsum, N_NODES);
    scan2_kernel<<<1, 512, 0, stream>>>(bsum, NB_SCAN);
    scan3_kernel<<<NB_SCAN, SCAN_B, 0, stream>>>(scanned, bsum, row_ptr, cursor, N_NODES, E);
    scatter_kernel<<<(E + 255) / 256, 256, 0, stream>>>(adj_rows, adj_cols, adj_vals,
                                                        cursor, pcol, pval, E);

    // ---- layer 1 ----
    gemm1_kernel<<<N_NODES / 4, 128, 0, stream>>>(x, W1, xw);
    {   // h = A_hat @ xw : 64 lanes/row, float2 per lane
        long long threads = (long long)N_NODES * 64;
        spmm_csr_kernel<HID_F, 64, 2><<<(int)((threads + 255) / 256), 256, 0, stream>>>(
            row_ptr, pcol, pval, xw, h);
    }

    // ---- layer 2 ----
    gemm2_kernel<<<N_NODES / 8, 256, 0, stream>>>(h, W2, hw);
    {   // out = A_hat @ hw : 32 lanes/row, 1 float per lane
        long long threads = (long long)N_NODES * 32;
        spmm_csr_kernel<OUT_F, 32, 1><<<(int)((threads + 255) / 256), 256, 0, stream>>>(
            row_ptr, pcol, pval, hw, out);
    }
}

// Round 3
// 649.124 us; speedup vs baseline: 5.7041x; 1.2143x over previous
//
#include <hip/hip_runtime.h>
#include <hip/hip_bf16.h>

#define N_NODES 100000
#define IN_F 256
#define HID_F 128
#define OUT_F 32
#define SCAN_B 256
#define NB_SCAN ((N_NODES + SCAN_B - 1) / SCAN_B)   // 391

typedef __bf16 bf16x8 __attribute__((ext_vector_type(8)));
typedef __bf16 bf16x4 __attribute__((ext_vector_type(4)));
typedef __bf16 bf16x2 __attribute__((ext_vector_type(2)));
typedef float  f32x4  __attribute__((ext_vector_type(4)));

// ---------------- conversions ----------------
__global__ void cvt_x_kernel(const float* __restrict__ in, __bf16* __restrict__ out,
                             long long n4) {
    long long i = (long long)blockIdx.x * blockDim.x + threadIdx.x;
    if (i >= n4) return;
    float4 f = ((const float4*)in)[i];
    bf16x4 o = { (__bf16)f.x, (__bf16)f.y, (__bf16)f.z, (__bf16)f.w };
    ((bf16x4*)out)[i] = o;
}

// W1 [256 k][128 n] f32 -> W1T [128 n][256 k] bf16
__global__ void cvt_w1t_kernel(const float* __restrict__ W1, __bf16* __restrict__ W1T) {
    int i = blockIdx.x * 256 + threadIdx.x;      // i = n*256 + k
    if (i >= IN_F * HID_F) return;
    int n = i >> 8, k = i & 255;
    W1T[i] = (__bf16)W1[k * HID_F + n];
}

// ---------------- GEMM1 (MFMA): xw_bf16 = bf16(x) @ bf16(W1) ----------------
// block: 256 threads (4 waves); 128 rows x 128 cols per block; K=256 in 2 halves.
__global__ __launch_bounds__(256)
void gemm1_mfma_kernel(const __bf16* __restrict__ xb,
                       const __bf16* __restrict__ W1T,
                       __bf16* __restrict__ xw) {
    const int r0   = blockIdx.x * 128;
    const int wv   = threadIdx.x >> 6;
    const int lane = threadIdx.x & 63;
    const int quad = lane >> 4;
    const int l15  = lane & 15;

    __shared__ __bf16 Bs[128][136];   // [n][k_half], pad 8 -> 272B stride (2-way/free)

    f32x4 acc[2][8];
#pragma unroll
    for (int rt = 0; rt < 2; ++rt)
#pragma unroll
        for (int nt = 0; nt < 8; ++nt)
            acc[rt][nt] = (f32x4){0.f, 0.f, 0.f, 0.f};

    for (int half = 0; half < 2; ++half) {
        // stage W1T[n][half*128 .. +127] into Bs (straight copy, coalesced)
        for (int i = threadIdx.x; i < 128 * 16; i += 256) {
            int n = i >> 4, kc = i & 15;
            bf16x8 w = *(const bf16x8*)(W1T + n * 256 + half * 128 + kc * 8);
            *(bf16x8*)(&Bs[n][kc * 8]) = w;
        }
        __syncthreads();

#pragma unroll
        for (int kt = 0; kt < 4; ++kt) {
            const int k0 = kt * 32;
            bf16x8 a[2];
#pragma unroll
            for (int rt = 0; rt < 2; ++rt) {
                int gm = r0 + wv * 32 + rt * 16 + l15;
                if (gm > N_NODES - 1) gm = N_NODES - 1;
                a[rt] = *(const bf16x8*)(xb + (size_t)gm * IN_F + half * 128 + k0 + quad * 8);
            }
            bf16x8 b[8];
#pragma unroll
            for (int nt = 0; nt < 8; ++nt)
                b[nt] = *(const bf16x8*)(&Bs[nt * 16 + l15][k0 + quad * 8]);
#pragma unroll
            for (int rt = 0; rt < 2; ++rt)
#pragma unroll
                for (int nt = 0; nt < 8; ++nt)
                    acc[rt][nt] = __builtin_amdgcn_mfma_f32_16x16x32_bf16(
                        a[rt], b[nt], acc[rt][nt], 0, 0, 0);
        }
        __syncthreads();
    }

    // store: C/D layout col = lane&15, row = quad*4 + reg
#pragma unroll
    for (int rt = 0; rt < 2; ++rt)
#pragma unroll
        for (int nt = 0; nt < 8; ++nt)
#pragma unroll
            for (int reg = 0; reg < 4; ++reg) {
                int row = r0 + wv * 32 + rt * 16 + quad * 4 + reg;
                if (row < N_NODES)
                    xw[(size_t)row * HID_F + nt * 16 + l15] = (__bf16)acc[rt][nt][reg];
            }
}

// ---------------- GEMM2: hw = relu(h) @ W2   [N,128]x[128,32] ----------------
__global__ void gemm2_kernel(const float* __restrict__ h,
                             const float* __restrict__ W2,
                             float* __restrict__ hw) {
    const int col = threadIdx.x & 31;
    const int rl  = threadIdx.x >> 5;
    const int row = blockIdx.x * 8 + rl;

    __shared__ float ws[HID_F * OUT_F];
    for (int i = threadIdx.x; i < HID_F * OUT_F; i += 256) ws[i] = W2[i];

    __shared__ float hs[8][HID_F];
    for (int i = threadIdx.x; i < 8 * HID_F; i += 256) {
        int r = i >> 7, k = i & (HID_F - 1);
        float v = h[(long long)(blockIdx.x * 8 + r) * HID_F + k];
        hs[r][k] = v > 0.f ? v : 0.f;
    }
    __syncthreads();

    float acc = 0.f;
#pragma unroll 8
    for (int k = 0; k < HID_F; ++k)
        acc += hs[rl][k] * ws[k * OUT_F + col];
    hw[(long long)row * OUT_F + col] = acc;
}

// ---------------- CSR build ----------------
__global__ void hist_kernel(const int* __restrict__ rows, int* __restrict__ cnt, int E) {
    int e = blockIdx.x * 256 + threadIdx.x;
    if (e < E) atomicAdd(&cnt[rows[e]], 1);
}

__global__ void scan1_kernel(const int* __restrict__ in, int* __restrict__ out,
                             int* __restrict__ bsum, int n) {
    __shared__ int tmp[SCAN_B];
    int i = blockIdx.x * SCAN_B + threadIdx.x;
    int v = (i < n) ? in[i] : 0;
    tmp[threadIdx.x] = v;
    __syncthreads();
    for (int off = 1; off < SCAN_B; off <<= 1) {
        int t = (threadIdx.x >= off) ? tmp[threadIdx.x - off] : 0;
        __syncthreads();
        tmp[threadIdx.x] += t;
        __syncthreads();
    }
    if (i < n) out[i] = tmp[threadIdx.x] - v;
    if (threadIdx.x == SCAN_B - 1) bsum[blockIdx.x] = tmp[SCAN_B - 1];
}

__global__ void scan2_kernel(int* __restrict__ bsum, int n) {
    __shared__ int tmp[512];
    int v = (threadIdx.x < n) ? bsum[threadIdx.x] : 0;
    tmp[threadIdx.x] = v;
    __syncthreads();
    for (int off = 1; off < 512; off <<= 1) {
        int t = (threadIdx.x >= off) ? tmp[threadIdx.x - off] : 0;
        __syncthreads();
        tmp[threadIdx.x] += t;
        __syncthreads();
    }
    if (threadIdx.x < n) bsum[threadIdx.x] = tmp[threadIdx.x] - v;
}

__global__ void scan3_kernel(const int* __restrict__ scanned,
                             const int* __restrict__ bsum,
                             int* __restrict__ row_ptr,
                             int* __restrict__ cursor, int n, int E) {
    int i = blockIdx.x * SCAN_B + threadIdx.x;
    if (i < n) {
        int v = scanned[i] + bsum[blockIdx.x];
        row_ptr[i] = v;
        cursor[i]  = v;
    }
    if (i == 0) row_ptr[n] = E;
}

__global__ void scatter_kernel(const int* __restrict__ rows, const int* __restrict__ cols,
                               const float* __restrict__ vals, int* __restrict__ cursor,
                               int* __restrict__ pcol, float* __restrict__ pval, int E) {
    int e = blockIdx.x * 256 + threadIdx.x;
    if (e < E) {
        int pos = atomicAdd(&cursor[rows[e]], 1);
        pcol[pos] = cols[e];
        pval[pos] = vals[e];
    }
}

// ---------------- SpMM via CSR gather ----------------
// layer 1: bf16 src, F=128, 64 lanes/row, 2 elems/lane, f32 accumulate/write
__global__ void spmm_csr_bf16_kernel(const int* __restrict__ row_ptr,
                                     const int* __restrict__ pcol,
                                     const float* __restrict__ pval,
                                     const __bf16* __restrict__ src,
                                     float* __restrict__ dst) {
    long long gid = (long long)blockIdx.x * blockDim.x + threadIdx.x;
    int row  = (int)(gid >> 6);
    int lane = (int)(gid & 63);
    if (row >= N_NODES) return;

    const int e0 = row_ptr[row];
    const int e1 = row_ptr[row + 1];

    float a0 = 0.f, a1 = 0.f;
    for (int e = e0; e < e1; ++e) {
        const int   c = pcol[e];
        const float v = pval[e];
        bf16x2 s = ((const bf16x2*)(src + (size_t)c * HID_F))[lane];
        a0 += v * (float)s.x;
        a1 += v * (float)s.y;
    }
    float2* d = (float2*)(dst + (size_t)row * HID_F);
    d[lane] = make_float2(a0, a1);
}

// layer 2: f32 src, F=32, 32 lanes/row, 1 elem/lane
__global__ void spmm_csr_f32_kernel(const int* __restrict__ row_ptr,
                                    const int* __restrict__ pcol,
                                    const float* __restrict__ pval,
                                    const float* __restrict__ src,
                                    float* __restrict__ dst) {
    long long gid = (long long)blockIdx.x * blockDim.x + threadIdx.x;
    int row  = (int)(gid >> 5);
    int lane = (int)(gid & 31);
    if (row >= N_NODES) return;

    const int e0 = row_ptr[row];
    const int e1 = row_ptr[row + 1];

    float acc = 0.f;
    for (int e = e0; e < e1; ++e) {
        const int   c = pcol[e];
        const float v = pval[e];
        acc += v * src[(size_t)c * OUT_F + lane];
    }
    dst[(size_t)row * OUT_F + lane] = acc;
}

extern "C" void kernel_launch(void* const* d_in, const int* in_sizes, int n_in,
                              void* d_out, int out_size, void* d_ws, size_t ws_size,
                              hipStream_t stream) {
    const float* x        = (const float*)d_in[0];
    const int*   adj_rows = (const int*)d_in[1];
    const int*   adj_cols = (const int*)d_in[2];
    const float* adj_vals = (const float*)d_in[3];
    const float* W1       = (const float*)d_in[4];
    const float* W2       = (const float*)d_in[5];
    float*       out      = (float*)d_out;
    const int E = in_sizes[1];

    // workspace carve-up
    char* p = (char*)d_ws;
    __bf16* xb   = (__bf16*)p;  p += (size_t)N_NODES * IN_F * sizeof(__bf16);   // 51.2 MB
    float*  h    = (float*)xb;  // ALIAS: h reuses xb (xb dead after gemm1; exactly 51.2 MB)
    __bf16* W1T  = (__bf16*)p;  p += (size_t)IN_F * HID_F * sizeof(__bf16);     // 64 KB
    __bf16* xw   = (__bf16*)p;  p += (size_t)N_NODES * HID_F * sizeof(__bf16);  // 25.6 MB
    float*  hw   = (float*)p;   p += (size_t)N_NODES * OUT_F * sizeof(float);   // 12.8 MB
    int*   cnt     = (int*)p;   p += (size_t)N_NODES * sizeof(int);
    int*   scanned = (int*)p;   p += (size_t)N_NODES * sizeof(int);
    int*   row_ptr = (int*)p;   p += (size_t)(N_NODES + 1) * sizeof(int);
    int*   cursor  = (int*)p;   p += (size_t)N_NODES * sizeof(int);
    int*   bsum    = (int*)p;   p += 1024 * sizeof(int);
    int*   pcol    = (int*)p;   p += (size_t)E * sizeof(int);
    float* pval    = (float*)p; p += (size_t)E * sizeof(float);

    // ---- CSR build (independent of feature pipeline) ----
    hipMemsetAsync(cnt, 0, (size_t)N_NODES * sizeof(int), stream);
    hist_kernel<<<(E + 255) / 256, 256, 0, stream>>>(adj_rows, cnt, E);
    scan1_kernel<<<NB_SCAN, SCAN_B, 0, stream>>>(cnt, scanned, bsum, N_NODES);
    scan2_kernel<<<1, 512, 0, stream>>>(bsum, NB_SCAN);
    scan3_kernel<<<NB_SCAN, SCAN_B, 0, stream>>>(scanned, bsum, row_ptr, cursor, N_NODES, E);
    scatter_kernel<<<(E + 255) / 256, 256, 0, stream>>>(adj_rows, adj_cols, adj_vals,
                                                        cursor, pcol, pval, E);

    // ---- conversions ----
    {
        long long n4 = (long long)N_NODES * IN_F / 4;
        cvt_x_kernel<<<(int)((n4 + 255) / 256), 256, 0, stream>>>(x, xb, n4);
        cvt_w1t_kernel<<<(IN_F * HID_F + 255) / 256, 256, 0, stream>>>(W1, W1T);
    }

    // ---- layer 1 ----
    gemm1_mfma_kernel<<<(N_NODES + 127) / 128, 256, 0, stream>>>(xb, W1T, xw);
    {   // h = A_hat @ xw (bf16 gather, f32 accum). NOTE: h aliases xb — xb fully consumed.
        long long threads = (long long)N_NODES * 64;
        spmm_csr_bf16_kernel<<<(int)((threads + 255) / 256), 256, 0, stream>>>(
            row_ptr, pcol, pval, xw, h);
    }

    // ---- layer 2 ----
    gemm2_kernel<<<N_NODES / 8, 256, 0, stream>>>(h, W2, hw);
    {
        long long threads = (long long)N_NODES * 32;
        spmm_csr_f32_kernel<<<(int)((threads + 255) / 256), 256, 0, stream>>>(
            row_ptr, pcol, pval, hw, out);
    }
}

// Round 4
// 457.394 us; speedup vs baseline: 8.0952x; 1.4192x over previous
//
#include <hip/hip_runtime.h>
#include <hip/hip_bf16.h>

#define N_NODES 100000
#define IN_F 256
#define HID_F 128
#define OUT_F 32
#define SCAN_B 256
#define NB_SCAN ((N_NODES + SCAN_B - 1) / SCAN_B)   // 391

typedef __bf16 bf16x8 __attribute__((ext_vector_type(8)));
typedef __bf16 bf16x4 __attribute__((ext_vector_type(4)));
typedef __bf16 bf16x2 __attribute__((ext_vector_type(2)));
typedef float  f32x4  __attribute__((ext_vector_type(4)));

// ---------------- W1 [256 k][128 n] f32 -> W1T [128 n][256 k] bf16 ----------------
__global__ void cvt_w1t_kernel(const float* __restrict__ W1, __bf16* __restrict__ W1T) {
    int i = blockIdx.x * 256 + threadIdx.x;      // i = n*256 + k
    if (i >= IN_F * HID_F) return;
    int n = i >> 8, k = i & 255;
    W1T[i] = (__bf16)W1[k * HID_F + n];
}

// ---------------- GEMM1 (MFMA): xw_bf16 = bf16(x) @ bf16(W1) ----------------
// 256 threads (4 waves); 128 rows x 128 cols per block; K=256 in 2 halves.
// A loaded as f32 from x and converted in-register (no separate cvt pass).
__global__ __launch_bounds__(256)
void gemm1_mfma_kernel(const float* __restrict__ x,
                       const __bf16* __restrict__ W1T,
                       __bf16* __restrict__ xw) {
    const int r0   = blockIdx.x * 128;
    const int wv   = threadIdx.x >> 6;
    const int lane = threadIdx.x & 63;
    const int quad = lane >> 4;
    const int l15  = lane & 15;

    __shared__ __bf16 Bs[128][136];   // [n][k_half], pad 8 -> 272B stride (2-way/free)

    f32x4 acc[2][8];
#pragma unroll
    for (int rt = 0; rt < 2; ++rt)
#pragma unroll
        for (int nt = 0; nt < 8; ++nt)
            acc[rt][nt] = (f32x4){0.f, 0.f, 0.f, 0.f};

    for (int half = 0; half < 2; ++half) {
        for (int i = threadIdx.x; i < 128 * 16; i += 256) {
            int n = i >> 4, kc = i & 15;
            bf16x8 w = *(const bf16x8*)(W1T + n * 256 + half * 128 + kc * 8);
            *(bf16x8*)(&Bs[n][kc * 8]) = w;
        }
        __syncthreads();

#pragma unroll
        for (int kt = 0; kt < 4; ++kt) {
            const int k0 = kt * 32;
            bf16x8 a[2];
#pragma unroll
            for (int rt = 0; rt < 2; ++rt) {
                int gm = r0 + wv * 32 + rt * 16 + l15;
                if (gm > N_NODES - 1) gm = N_NODES - 1;
                const float* xp = x + (size_t)gm * IN_F + half * 128 + k0 + quad * 8;
                float4 f0 = *(const float4*)xp;
                float4 f1 = *(const float4*)(xp + 4);
                a[rt] = (bf16x8){ (__bf16)f0.x, (__bf16)f0.y, (__bf16)f0.z, (__bf16)f0.w,
                                  (__bf16)f1.x, (__bf16)f1.y, (__bf16)f1.z, (__bf16)f1.w };
            }
            bf16x8 b[8];
#pragma unroll
            for (int nt = 0; nt < 8; ++nt)
                b[nt] = *(const bf16x8*)(&Bs[nt * 16 + l15][k0 + quad * 8]);
#pragma unroll
            for (int rt = 0; rt < 2; ++rt)
#pragma unroll
                for (int nt = 0; nt < 8; ++nt)
                    acc[rt][nt] = __builtin_amdgcn_mfma_f32_16x16x32_bf16(
                        a[rt], b[nt], acc[rt][nt], 0, 0, 0);
        }
        __syncthreads();
    }

#pragma unroll
    for (int rt = 0; rt < 2; ++rt)
#pragma unroll
        for (int nt = 0; nt < 8; ++nt)
#pragma unroll
            for (int reg = 0; reg < 4; ++reg) {
                int row = r0 + wv * 32 + rt * 16 + quad * 4 + reg;
                if (row < N_NODES)
                    xw[(size_t)row * HID_F + nt * 16 + l15] = (__bf16)acc[rt][nt][reg];
            }
}

// ---------------- GEMM2 (MFMA): hw_bf16 = h_bf16 @ bf16(W2) ----------------
// 256 threads (4 waves); 128 rows x 32 cols per block; K=128.
__global__ __launch_bounds__(256)
void gemm2_mfma_kernel(const __bf16* __restrict__ h,
                       const float* __restrict__ W2,
                       __bf16* __restrict__ hw) {
    const int r0   = blockIdx.x * 128;
    const int wv   = threadIdx.x >> 6;
    const int lane = threadIdx.x & 63;
    const int quad = lane >> 4;
    const int l15  = lane & 15;

    __shared__ __bf16 W2T[32][136];   // [n][k], pad 8 -> 272B stride

    for (int i = threadIdx.x; i < 32 * 128; i += 256) {
        int n = i & 31, k = i >> 5;
        W2T[n][k] = (__bf16)W2[k * OUT_F + n];
    }
    __syncthreads();

    f32x4 acc[2][2];
#pragma unroll
    for (int rt = 0; rt < 2; ++rt)
#pragma unroll
        for (int nt = 0; nt < 2; ++nt)
            acc[rt][nt] = (f32x4){0.f, 0.f, 0.f, 0.f};

#pragma unroll
    for (int kt = 0; kt < 4; ++kt) {
        const int k0 = kt * 32;
        bf16x8 a[2];
#pragma unroll
        for (int rt = 0; rt < 2; ++rt) {
            int gm = r0 + wv * 32 + rt * 16 + l15;
            if (gm > N_NODES - 1) gm = N_NODES - 1;
            a[rt] = *(const bf16x8*)(h + (size_t)gm * HID_F + k0 + quad * 8);
        }
        bf16x8 b[2];
#pragma unroll
        for (int nt = 0; nt < 2; ++nt)
            b[nt] = *(const bf16x8*)(&W2T[nt * 16 + l15][k0 + quad * 8]);
#pragma unroll
        for (int rt = 0; rt < 2; ++rt)
#pragma unroll
            for (int nt = 0; nt < 2; ++nt)
                acc[rt][nt] = __builtin_amdgcn_mfma_f32_16x16x32_bf16(
                    a[rt], b[nt], acc[rt][nt], 0, 0, 0);
    }

#pragma unroll
    for (int rt = 0; rt < 2; ++rt)
#pragma unroll
        for (int nt = 0; nt < 2; ++nt)
#pragma unroll
            for (int reg = 0; reg < 4; ++reg) {
                int row = r0 + wv * 32 + rt * 16 + quad * 4 + reg;
                if (row < N_NODES)
                    hw[(size_t)row * OUT_F + nt * 16 + l15] = (__bf16)acc[rt][nt][reg];
            }
}

// ---------------- CSR build ----------------
__global__ void hist_kernel(const int* __restrict__ rows, int* __restrict__ cnt, int E) {
    int e = blockIdx.x * 256 + threadIdx.x;
    if (e < E) atomicAdd(&cnt[rows[e]], 1);
}

__global__ void scan1_kernel(const int* __restrict__ in, int* __restrict__ out,
                             int* __restrict__ bsum, int n) {
    __shared__ int tmp[SCAN_B];
    int i = blockIdx.x * SCAN_B + threadIdx.x;
    int v = (i < n) ? in[i] : 0;
    tmp[threadIdx.x] = v;
    __syncthreads();
    for (int off = 1; off < SCAN_B; off <<= 1) {
        int t = (threadIdx.x >= off) ? tmp[threadIdx.x - off] : 0;
        __syncthreads();
        tmp[threadIdx.x] += t;
        __syncthreads();
    }
    if (i < n) out[i] = tmp[threadIdx.x] - v;
    if (threadIdx.x == SCAN_B - 1) bsum[blockIdx.x] = tmp[SCAN_B - 1];
}

__global__ void scan2_kernel(int* __restrict__ bsum, int n) {
    __shared__ int tmp[512];
    int v = (threadIdx.x < n) ? bsum[threadIdx.x] : 0;
    tmp[threadIdx.x] = v;
    __syncthreads();
    for (int off = 1; off < 512; off <<= 1) {
        int t = (threadIdx.x >= off) ? tmp[threadIdx.x - off] : 0;
        __syncthreads();
        tmp[threadIdx.x] += t;
        __syncthreads();
    }
    if (threadIdx.x < n) bsum[threadIdx.x] = tmp[threadIdx.x] - v;
}

__global__ void scan3_kernel(const int* __restrict__ scanned,
                             const int* __restrict__ bsum,
                             int* __restrict__ row_ptr,
                             int* __restrict__ cursor, int n, int E) {
    int i = blockIdx.x * SCAN_B + threadIdx.x;
    if (i < n) {
        int v = scanned[i] + bsum[blockIdx.x];
        row_ptr[i] = v;
        cursor[i]  = v;
    }
    if (i == 0) row_ptr[n] = E;
}

__global__ void scatter_kernel(const int* __restrict__ rows, const int* __restrict__ cols,
                               const float* __restrict__ vals, int* __restrict__ cursor,
                               int* __restrict__ pcol, float* __restrict__ pval, int E) {
    int e = blockIdx.x * 256 + threadIdx.x;
    if (e < E) {
        int pos = atomicAdd(&cursor[rows[e]], 1);
        pcol[pos] = cols[e];
        pval[pos] = vals[e];
    }
}

// ---------------- SpMM layer 1: h_bf16 = relu(A @ xw_bf16) ----------------
// one 64-lane wave per row; lane owns 2 features (bf16x2 = 4B); 4-way edge unroll.
__global__ __launch_bounds__(256)
void spmm1_kernel(const int* __restrict__ row_ptr,
                  const int* __restrict__ pcol,
                  const float* __restrict__ pval,
                  const __bf16* __restrict__ src,
                  __bf16* __restrict__ dst) {
    int row = __builtin_amdgcn_readfirstlane(blockIdx.x * 4 + (threadIdx.x >> 6));
    int lane = threadIdx.x & 63;
    if (row >= N_NODES) return;

    const int e0 = row_ptr[row];
    const int e1 = row_ptr[row + 1];

    float a0 = 0.f, a1 = 0.f;
    int e = e0;
    for (; e + 4 <= e1; e += 4) {
        int   c0 = pcol[e],   c1 = pcol[e+1], c2 = pcol[e+2], c3 = pcol[e+3];
        float v0 = pval[e],   v1 = pval[e+1], v2 = pval[e+2], v3 = pval[e+3];
        bf16x2 s0 = ((const bf16x2*)(src + (size_t)c0 * HID_F))[lane];
        bf16x2 s1 = ((const bf16x2*)(src + (size_t)c1 * HID_F))[lane];
        bf16x2 s2 = ((const bf16x2*)(src + (size_t)c2 * HID_F))[lane];
        bf16x2 s3 = ((const bf16x2*)(src + (size_t)c3 * HID_F))[lane];
        a0 += v0 * (float)s0.x + v1 * (float)s1.x + v2 * (float)s2.x + v3 * (float)s3.x;
        a1 += v0 * (float)s0.y + v1 * (float)s1.y + v2 * (float)s2.y + v3 * (float)s3.y;
    }
    for (; e < e1; ++e) {
        int   c = pcol[e];
        float v = pval[e];
        bf16x2 s = ((const bf16x2*)(src + (size_t)c * HID_F))[lane];
        a0 += v * (float)s.x;
        a1 += v * (float)s.y;
    }
    a0 = fmaxf(a0, 0.f);                 // fused relu
    a1 = fmaxf(a1, 0.f);
    bf16x2 o = { (__bf16)a0, (__bf16)a1 };
    ((bf16x2*)(dst + (size_t)row * HID_F))[lane] = o;
}

// ---------------- SpMM layer 2: out_f32 = A @ hw_bf16 ----------------
// 16 lanes per row (bf16x2 each = 64B row); 4 rows per wave; 4-way edge unroll.
__global__ __launch_bounds__(256)
void spmm2_kernel(const int* __restrict__ row_ptr,
                  const int* __restrict__ pcol,
                  const float* __restrict__ pval,
                  const __bf16* __restrict__ src,
                  float* __restrict__ dst) {
    long long gid = (long long)blockIdx.x * 256 + threadIdx.x;
    int row  = (int)(gid >> 4);
    int lane = (int)(gid & 15);
    if (row >= N_NODES) return;

    const int e0 = row_ptr[row];
    const int e1 = row_ptr[row + 1];

    float a0 = 0.f, a1 = 0.f;
    int e = e0;
    for (; e + 4 <= e1; e += 4) {
        int   c0 = pcol[e],   c1 = pcol[e+1], c2 = pcol[e+2], c3 = pcol[e+3];
        float v0 = pval[e],   v1 = pval[e+1], v2 = pval[e+2], v3 = pval[e+3];
        bf16x2 s0 = ((const bf16x2*)(src + (size_t)c0 * OUT_F))[lane];
        bf16x2 s1 = ((const bf16x2*)(src + (size_t)c1 * OUT_F))[lane];
        bf16x2 s2 = ((const bf16x2*)(src + (size_t)c2 * OUT_F))[lane];
        bf16x2 s3 = ((const bf16x2*)(src + (size_t)c3 * OUT_F))[lane];
        a0 += v0 * (float)s0.x + v1 * (float)s1.x + v2 * (float)s2.x + v3 * (float)s3.x;
        a1 += v0 * (float)s0.y + v1 * (float)s1.y + v2 * (float)s2.y + v3 * (float)s3.y;
    }
    for (; e < e1; ++e) {
        int   c = pcol[e];
        float v = pval[e];
        bf16x2 s = ((const bf16x2*)(src + (size_t)c * OUT_F))[lane];
        a0 += v * (float)s.x;
        a1 += v * (float)s.y;
    }
    ((float2*)(dst + (size_t)row * OUT_F))[lane] = make_float2(a0, a1);
}

extern "C" void kernel_launch(void* const* d_in, const int* in_sizes, int n_in,
                              void* d_out, int out_size, void* d_ws, size_t ws_size,
                              hipStream_t stream) {
    const float* x        = (const float*)d_in[0];
    const int*   adj_rows = (const int*)d_in[1];
    const int*   adj_cols = (const int*)d_in[2];
    const float* adj_vals = (const float*)d_in[3];
    const float* W1       = (const float*)d_in[4];
    const float* W2       = (const float*)d_in[5];
    float*       out      = (float*)d_out;
    const int E = in_sizes[1];

    char* p = (char*)d_ws;
    __bf16* W1T  = (__bf16*)p;  p += (size_t)IN_F * HID_F * sizeof(__bf16);     // 64 KB
    __bf16* xw   = (__bf16*)p;  p += (size_t)N_NODES * HID_F * sizeof(__bf16);  // 25.6 MB
    __bf16* h    = (__bf16*)p;  p += (size_t)N_NODES * HID_F * sizeof(__bf16);  // 25.6 MB
    __bf16* hw   = (__bf16*)p;  p += (size_t)N_NODES * OUT_F * sizeof(__bf16);  // 6.4 MB
    int*   cnt     = (int*)p;   p += (size_t)N_NODES * sizeof(int);
    int*   scanned = (int*)p;   p += (size_t)N_NODES * sizeof(int);
    int*   row_ptr = (int*)p;   p += (size_t)(N_NODES + 1) * sizeof(int);
    int*   cursor  = (int*)p;   p += (size_t)N_NODES * sizeof(int);
    int*   bsum    = (int*)p;   p += 1024 * sizeof(int);
    int*   pcol    = (int*)p;   p += (size_t)E * sizeof(int);                   // 6.4 MB
    float* pval    = (float*)p; p += (size_t)E * sizeof(float);                 // 6.4 MB

    // ---- CSR build ----
    hipMemsetAsync(cnt, 0, (size_t)N_NODES * sizeof(int), stream);
    hist_kernel<<<(E + 255) / 256, 256, 0, stream>>>(adj_rows, cnt, E);
    scan1_kernel<<<NB_SCAN, SCAN_B, 0, stream>>>(cnt, scanned, bsum, N_NODES);
    scan2_kernel<<<1, 512, 0, stream>>>(bsum, NB_SCAN);
    scan3_kernel<<<NB_SCAN, SCAN_B, 0, stream>>>(scanned, bsum, row_ptr, cursor, N_NODES, E);
    scatter_kernel<<<(E + 255) / 256, 256, 0, stream>>>(adj_rows, adj_cols, adj_vals,
                                                        cursor, pcol, pval, E);

    cvt_w1t_kernel<<<(IN_F * HID_F + 255) / 256, 256, 0, stream>>>(W1, W1T);

    // ---- layer 1 ----
    gemm1_mfma_kernel<<<(N_NODES + 127) / 128, 256, 0, stream>>>(x, W1T, xw);
    spmm1_kernel<<<(N_NODES + 3) / 4, 256, 0, stream>>>(row_ptr, pcol, pval, xw, h);

    // ---- layer 2 ----
    gemm2_mfma_kernel<<<(N_NODES + 127) / 128, 256, 0, stream>>>(h, W2, hw);
    {
        long long threads = (long long)N_NODES * 16;
        spmm2_kernel<<<(int)((threads + 255) / 256), 256, 0, stream>>>(
            row_ptr, pcol, pval, hw, out);
    }
}